// Round 1
// baseline (984.112 us; speedup 1.0000x reference)
//
#include <hip/hip_runtime.h>

using short8  = __attribute__((ext_vector_type(8))) short;
using ushort8 = __attribute__((ext_vector_type(8))) unsigned short;
using f32x16  = __attribute__((ext_vector_type(16))) float;

#define T   4096
#define E   1024
#define NB  2
#define TQ  32
#define TK  128
#define VT_ROWS 1056   // 1024 data rows + 1 ones row + 31 zero rows (pad to tile)

__device__ inline unsigned short f2bf(float f) {
    unsigned int u = __builtin_bit_cast(unsigned int, f);
    u = (u + 0x7FFFu + ((u >> 16) & 1u)) >> 16;
    return (unsigned short)u;
}

// fp32 [*] -> bf16 [*] (same layout), 8 elems/thread
__global__ __launch_bounds__(256) void cvt_bf16(const float* __restrict__ src,
                                                unsigned short* __restrict__ dst) {
    size_t i = ((size_t)blockIdx.x * 256 + threadIdx.x) * 8;
    float4 f0 = *(const float4*)(src + i);
    float4 f1 = *(const float4*)(src + i + 4);
    ushort8 u;
    u[0]=f2bf(f0.x); u[1]=f2bf(f0.y); u[2]=f2bf(f0.z); u[3]=f2bf(f0.w);
    u[4]=f2bf(f1.x); u[5]=f2bf(f1.y); u[6]=f2bf(f1.z); u[7]=f2bf(f1.w);
    *(ushort8*)(dst + i) = u;
}

// V [b][t][e] fp32 -> VT [b][e][t] bf16, 64x64 tiles through LDS
__global__ __launch_bounds__(256) void v_transpose(const float* __restrict__ v,
                                                   unsigned short* __restrict__ vt) {
    __shared__ float tile[64][65];
    int id  = blockIdx.x;
    int b   = id / (64 * 16);
    int rem = id % (64 * 16);
    int t0  = (rem / 16) * 64;
    int e0  = (rem % 16) * 64;
    int tid = threadIdx.x;
    int r   = tid >> 2;
    int c0  = (tid & 3) * 16;
    const float* src = v + ((size_t)(b * T + t0 + r)) * E + e0 + c0;
    #pragma unroll
    for (int i = 0; i < 4; i++) {
        float4 f = *(const float4*)(src + i * 4);
        tile[r][c0 + i*4 + 0] = f.x;
        tile[r][c0 + i*4 + 1] = f.y;
        tile[r][c0 + i*4 + 2] = f.z;
        tile[r][c0 + i*4 + 3] = f.w;
    }
    __syncthreads();
    int er = tid >> 2;
    #pragma unroll
    for (int ch = 0; ch < 2; ch++) {
        int tl = (tid & 3) * 16 + ch * 8;
        ushort8 u;
        #pragma unroll
        for (int j = 0; j < 8; j++) u[j] = f2bf(tile[tl + j][er]);
        *(ushort8*)(vt + ((size_t)(b * VT_ROWS + e0 + er)) * T + t0 + tl) = u;
    }
}

// rows 1024..1055 of VT: row 1024 = ones (softmax denominator trick), rest zeros
__global__ __launch_bounds__(256) void vt_tail(unsigned short* __restrict__ vt) {
    int idx = blockIdx.x * 256 + threadIdx.x;
    int b   = idx / (32 * T);
    int rem = idx % (32 * T);
    int er  = rem / T;
    int t   = rem % T;
    vt[((size_t)(b * VT_ROWS + 1024 + er)) * T + t] = (er == 0) ? 0x3F80 : 0;
}

// Flash attention, no-max softmax (exp2(s*scale*log2e - 12), normalize at end).
// grid = 2 batches * 128 q-tiles; block = 256 (4 waves).
// Wave w: S cols kr in [32w,32w+32); O cols e in [256w, 256w+256).
__global__ __launch_bounds__(256, 1) void attn_main(const float* __restrict__ q_unused,
        const unsigned short* __restrict__ qb,
        const unsigned short* __restrict__ kb,
        const unsigned short* __restrict__ vt,
        float* __restrict__ out) {
    __shared__ unsigned short ps[TQ * 136];   // P tile, pitch 136 (bank-stride 4, 16B-aligned)

    const int bx   = blockIdx.x;
    const int b    = bx >> 7;
    const int q0   = (bx & 127) * TQ;
    const int tid  = threadIdx.x;
    const int lane = tid & 63;
    const int wave = tid >> 6;
    const int l31  = lane & 31;
    const int half = lane >> 5;

    f32x16 oacc[8];
    #pragma unroll
    for (int i = 0; i < 8; i++) oacc[i] = {};
    f32x16 lacc = {};

    const unsigned short* qbase = qb + ((size_t)(b * T + q0 + l31)) * E + half * 8;
    const unsigned short* pfragbase = ps + l31 * 136 + half * 8;
    const float sl2 = 0.0625f * 1.44269504f;   // scale * log2(e)

    for (int kt = 0; kt < T / TK; kt++) {
        // ---- S = Q @ K^T (this wave's 32 kr columns), contract e=1024 in 64 steps ----
        const unsigned short* kbase =
            kb + ((size_t)(b * T + kt * TK + wave * 32 + l31)) * E + half * 8;
        f32x16 s0 = {}, s1 = {}, s2 = {}, s3 = {};
        #pragma unroll 2
        for (int s = 0; s < 64; s += 4) {
            short8 a0 = *(const short8*)(qbase + 16 * s);
            short8 b0 = *(const short8*)(kbase + 16 * s);
            s0 = __builtin_amdgcn_mfma_f32_32x32x16_bf16(a0, b0, s0, 0, 0, 0);
            short8 a1 = *(const short8*)(qbase + 16 * (s + 1));
            short8 b1 = *(const short8*)(kbase + 16 * (s + 1));
            s1 = __builtin_amdgcn_mfma_f32_32x32x16_bf16(a1, b1, s1, 0, 0, 0);
            short8 a2 = *(const short8*)(qbase + 16 * (s + 2));
            short8 b2 = *(const short8*)(kbase + 16 * (s + 2));
            s2 = __builtin_amdgcn_mfma_f32_32x32x16_bf16(a2, b2, s2, 0, 0, 0);
            short8 a3 = *(const short8*)(qbase + 16 * (s + 3));
            short8 b3 = *(const short8*)(kbase + 16 * (s + 3));
            s3 = __builtin_amdgcn_mfma_f32_32x32x16_bf16(a3, b3, s3, 0, 0, 0);
        }
        f32x16 sv = (s0 + s1) + (s2 + s3);

        __syncthreads();   // all waves done reading previous P
        {
            // C/D layout (m74/m101): col = lane&31, row = (reg&3) + 8*(reg>>2) + 4*(lane>>5)
            int pcol = wave * 32 + l31;
            #pragma unroll
            for (int r2 = 0; r2 < 16; r2++) {
                float p = exp2f(sv[r2] * sl2 - 12.0f);
                int prow = (r2 & 3) + 8 * (r2 >> 2) + 4 * half;
                ps[prow * 136 + pcol] = f2bf(p);
            }
        }
        __syncthreads();   // P ready

        // ---- O += P @ V (wave's 256 e-cols), l += P @ ones ----
        const unsigned short* vbase =
            vt + ((size_t)(b * VT_ROWS + wave * 256 + l31)) * T + kt * TK + half * 8;
        const unsigned short* lbase =
            vt + ((size_t)(b * VT_ROWS + 1024 + l31)) * T + kt * TK + half * 8;
        #pragma unroll
        for (int ct = 0; ct < 8; ct += 2) {
            const unsigned short* v0 = vbase + (size_t)(ct + 0) * 32 * T;
            const unsigned short* v1 = vbase + (size_t)(ct + 1) * 32 * T;
            #pragma unroll
            for (int ks = 0; ks < 8; ks++) {
                short8 pa  = *(const short8*)(pfragbase + 16 * ks);
                short8 vb0 = *(const short8*)(v0 + 16 * ks);
                short8 vb1 = *(const short8*)(v1 + 16 * ks);
                oacc[ct + 0] = __builtin_amdgcn_mfma_f32_32x32x16_bf16(pa, vb0, oacc[ct + 0], 0, 0, 0);
                oacc[ct + 1] = __builtin_amdgcn_mfma_f32_32x32x16_bf16(pa, vb1, oacc[ct + 1], 0, 0, 0);
            }
        }
        #pragma unroll
        for (int ks = 0; ks < 8; ks++) {
            short8 pa = *(const short8*)(pfragbase + 16 * ks);
            short8 lb = *(const short8*)(lbase + 16 * ks);
            lacc = __builtin_amdgcn_mfma_f32_32x32x16_bf16(pa, lb, lacc, 0, 0, 0);
        }
    }

    // ---- epilogue: O / l, store fp32 ----
    float* obase = out + ((size_t)(b * T + q0)) * E + wave * 256 + l31;
    #pragma unroll
    for (int r2 = 0; r2 < 16; r2++) {
        float lv = __shfl(lacc[r2], (lane & 32), 64);   // l lives in col 0 -> lanes 0 and 32
        float rv = 1.0f / lv;
        int orow = (r2 & 3) + 8 * (r2 >> 2) + 4 * half;
        float* op = obase + (size_t)orow * E;
        #pragma unroll
        for (int ct = 0; ct < 8; ct++) op[ct * 32] = oacc[ct][r2] * rv;
    }
}

extern "C" void kernel_launch(void* const* d_in, const int* in_sizes, int n_in,
                              void* d_out, int out_size, void* d_ws, size_t ws_size,
                              hipStream_t stream) {
    const float* q = (const float*)d_in[0];
    const float* k = (const float*)d_in[1];
    const float* v = (const float*)d_in[2];
    float* out = (float*)d_out;

    // ws layout: QB bf16 (16.78 MB) | KB bf16 (16.78 MB) | VT bf16 (17.3 MB) = ~50.9 MB
    unsigned short* qbw = (unsigned short*)d_ws;
    unsigned short* kbw = qbw + (size_t)NB * T * E;
    unsigned short* vtw = kbw + (size_t)NB * T * E;

    const int cvt_blocks = (int)((size_t)NB * T * E / (256 * 8));   // 4096
    cvt_bf16<<<cvt_blocks, 256, 0, stream>>>(q, qbw);
    cvt_bf16<<<cvt_blocks, 256, 0, stream>>>(k, kbw);
    v_transpose<<<NB * 64 * 16, 256, 0, stream>>>(v, vtw);
    vt_tail<<<NB * 32 * T / 256, 256, 0, stream>>>(vtw);

    attn_main<<<NB * (T / TQ), 256, 0, stream>>>(q, qbw, kbw, vtw, out);
}

// Round 2
// 392.258 us; speedup vs baseline: 2.5088x; 2.5088x over previous
//
#include <hip/hip_runtime.h>

using short8  = __attribute__((ext_vector_type(8))) short;
using ushort8 = __attribute__((ext_vector_type(8))) unsigned short;
using f32x16  = __attribute__((ext_vector_type(16))) float;

#define T 4096
#define E 1024
#define NB 2
#define BM 128
#define BN 128
#define BK 32

__device__ __forceinline__ unsigned short f2bf(float f) {
    unsigned int u = __builtin_bit_cast(unsigned int, f);
    u = (u + 0x7FFFu + ((u >> 16) & 1u)) >> 16;
    return (unsigned short)u;
}
__device__ __forceinline__ float bf2f(unsigned short h) {
    unsigned int u = ((unsigned int)h) << 16;
    return __builtin_bit_cast(float, u);
}

// async global->LDS, 16B per lane; LDS dest = wave-uniform base + lane*16
__device__ __forceinline__ void gld16(const unsigned short* g, unsigned short* l) {
    __builtin_amdgcn_global_load_lds(
        (__attribute__((address_space(1))) void*)g,
        (__attribute__((address_space(3))) void*)l, 16, 0, 0);
}

// fp32 -> bf16 same layout
__global__ __launch_bounds__(256) void cvt_bf16(const float* __restrict__ src,
                                                unsigned short* __restrict__ dst) {
    size_t i = ((size_t)blockIdx.x * 256 + threadIdx.x) * 8;
    float4 f0 = *(const float4*)(src + i);
    float4 f1 = *(const float4*)(src + i + 4);
    ushort8 u;
    u[0]=f2bf(f0.x); u[1]=f2bf(f0.y); u[2]=f2bf(f0.z); u[3]=f2bf(f0.w);
    u[4]=f2bf(f1.x); u[5]=f2bf(f1.y); u[6]=f2bf(f1.z); u[7]=f2bf(f1.w);
    *(ushort8*)(dst + i) = u;
}

// V [b][t][e] fp32 -> VT [b][e][t] bf16
__global__ __launch_bounds__(256) void v_transpose(const float* __restrict__ v,
                                                   unsigned short* __restrict__ vt) {
    __shared__ float tile[64][65];
    int id  = blockIdx.x;
    int b   = id / (64 * 16);
    int rem = id % (64 * 16);
    int t0  = (rem / 16) * 64;
    int e0  = (rem % 16) * 64;
    int tid = threadIdx.x;
    int r   = tid >> 2;
    int c0  = (tid & 3) * 16;
    const float* src = v + ((size_t)(b * T + t0 + r)) * E + e0 + c0;
    #pragma unroll
    for (int i = 0; i < 4; i++) {
        float4 f = *(const float4*)(src + i * 4);
        tile[r][c0 + i*4 + 0] = f.x;
        tile[r][c0 + i*4 + 1] = f.y;
        tile[r][c0 + i*4 + 2] = f.z;
        tile[r][c0 + i*4 + 3] = f.w;
    }
    __syncthreads();
    int er = tid >> 2;
    #pragma unroll
    for (int ch = 0; ch < 2; ch++) {
        int tl = (tid & 3) * 16 + ch * 8;
        ushort8 u;
        #pragma unroll
        for (int j = 0; j < 8; j++) u[j] = f2bf(tile[tl + j][er]);
        *(ushort8*)(vt + ((size_t)(b * E + e0 + er)) * T + t0 + tl) = u;
    }
}

__global__ __launch_bounds__(256) void zerof(float* __restrict__ p) {
    p[blockIdx.x * 256 + threadIdx.x] = 0.0f;
}

// Shared 128x128xBK GEMM core (m97 structure).
// LDS layout: chunk n (16B) -> row=(n&255)>>1, hf=n&1, ks=n>>8 ; elem addr = ks*2048 + row*16 + hf*8
// Both the global_load_lds scatter and the ds_read_b128 frag reads are
// permutations of contiguous 1KB per wave -> conflict-free.
template <int KITERS>
__device__ __forceinline__ void gemm_core(const unsigned short* Abase, int apitch,
                                          const unsigned short* Bbase, int bpitch,
                                          unsigned short* ldsA, unsigned short* ldsB,
                                          int tid, f32x16 (&acc)[2][2]) {
    const int lane = tid & 63, wave = tid >> 6;
    const int l31 = lane & 31, half = lane >> 5;
    const int mbase = (wave & 1) * 64, nbase = (wave >> 1) * 64;

    const unsigned short* ga[2];
    const unsigned short* gb[2];
    unsigned short* la[2];
    unsigned short* lb[2];
    #pragma unroll
    for (int i = 0; i < 2; i++) {
        int n = i * 256 + tid;
        int ks = n >> 8, row = (n & 255) >> 1, hf = n & 1;
        ga[i] = Abase + (size_t)row * apitch + ks * 16 + hf * 8;
        gb[i] = Bbase + (size_t)row * bpitch + ks * 16 + hf * 8;
        la[i] = ldsA + (i * 256 + wave * 64) * 8;
        lb[i] = ldsB + (i * 256 + wave * 64) * 8;
    }
    const int aoff0 = (mbase + l31) * 16 + half * 8;
    const int aoff1 = (mbase + 32 + l31) * 16 + half * 8;
    const int boff0 = (nbase + l31) * 16 + half * 8;
    const int boff1 = (nbase + 32 + l31) * 16 + half * 8;

    for (int kt = 0; kt < KITERS; kt++) {
        __syncthreads();
        gld16(ga[0] + kt * BK, la[0]);
        gld16(ga[1] + kt * BK, la[1]);
        gld16(gb[0] + kt * BK, lb[0]);
        gld16(gb[1] + kt * BK, lb[1]);
        __syncthreads();
        #pragma unroll
        for (int ks = 0; ks < 2; ks++) {
            const unsigned short* A = ldsA + ks * 2048;
            const unsigned short* B = ldsB + ks * 2048;
            short8 a0 = *(const short8*)(A + aoff0);
            short8 a1 = *(const short8*)(A + aoff1);
            short8 b0 = *(const short8*)(B + boff0);
            short8 b1 = *(const short8*)(B + boff1);
            acc[0][0] = __builtin_amdgcn_mfma_f32_32x32x16_bf16(a0, b0, acc[0][0], 0, 0, 0);
            acc[0][1] = __builtin_amdgcn_mfma_f32_32x32x16_bf16(a0, b1, acc[0][1], 0, 0, 0);
            acc[1][0] = __builtin_amdgcn_mfma_f32_32x32x16_bf16(a1, b0, acc[1][0], 0, 0, 0);
            acc[1][1] = __builtin_amdgcn_mfma_f32_32x32x16_bf16(a1, b1, acc[1][1], 0, 0, 0);
        }
    }
}

// Pass 1: P = exp2(scale*log2e*(Q K^T) - 12) [bf16], lsum += row sums [fp32]
__global__ __launch_bounds__(256, 2) void pass1(const unsigned short* __restrict__ qb,
                                                const unsigned short* __restrict__ kb,
                                                unsigned short* __restrict__ P,
                                                float* __restrict__ lsum) {
    __shared__ unsigned short ldsA[BM * BK];
    __shared__ unsigned short ldsB[BN * BK];
    const int bx = blockIdx.x;
    const int b = bx >> 10, mt = (bx >> 5) & 31, nt = bx & 31;
    const int tid = threadIdx.x;

    f32x16 acc[2][2];
    #pragma unroll
    for (int i = 0; i < 2; i++) { acc[i][0] = {}; acc[i][1] = {}; }

    gemm_core<E / BK>(qb + ((size_t)b * T + mt * BM) * E, E,
                      kb + ((size_t)b * T + nt * BN) * E, E,
                      ldsA, ldsB, tid, acc);

    const int lane = tid & 63, wave = tid >> 6;
    const int l31 = lane & 31, half = lane >> 5;
    const int mbase = (wave & 1) * 64, nbase = (wave >> 1) * 64;
    const float sl2 = 0.0625f * 1.44269504089f;

    #pragma unroll
    for (int mi = 0; mi < 2; mi++) {
        const int rowb = mt * BM + mbase + mi * 32;
        #pragma unroll
        for (int r = 0; r < 16; r++) {
            int rowit = (r & 3) + 8 * (r >> 2) + 4 * half;
            int row = rowb + rowit;
            float p0 = exp2f(acc[mi][0][r] * sl2 - 12.0f);
            float p1 = exp2f(acc[mi][1][r] * sl2 - 12.0f);
            unsigned short h0 = f2bf(p0), h1 = f2bf(p1);
            size_t base = ((size_t)b * T + row) * T + nt * BN + nbase + l31;
            P[base] = h0;
            P[base + 32] = h1;
            float s = bf2f(h0) + bf2f(h1);
            s += __shfl_xor(s, 1);
            s += __shfl_xor(s, 2);
            s += __shfl_xor(s, 4);
            s += __shfl_xor(s, 8);
            s += __shfl_xor(s, 16);
            if (l31 == 0) atomicAdd(lsum + b * T + row, s);
        }
    }
}

// Pass 2: O = (P @ V) / l ; B operand = VT [b][e][t]
__global__ __launch_bounds__(256, 2) void pass2(const unsigned short* __restrict__ P,
                                                const unsigned short* __restrict__ vt,
                                                const float* __restrict__ lsum,
                                                float* __restrict__ out) {
    __shared__ unsigned short ldsA[BM * BK];
    __shared__ unsigned short ldsB[BN * BK];
    const int bx = blockIdx.x;
    const int b = bx >> 8, mt = (bx >> 3) & 31, nt = bx & 7;
    const int tid = threadIdx.x;

    f32x16 acc[2][2];
    #pragma unroll
    for (int i = 0; i < 2; i++) { acc[i][0] = {}; acc[i][1] = {}; }

    gemm_core<T / BK>(P + ((size_t)b * T + mt * BM) * T, T,
                      vt + ((size_t)b * E + nt * BN) * T, T,
                      ldsA, ldsB, tid, acc);

    const int lane = tid & 63, wave = tid >> 6;
    const int l31 = lane & 31, half = lane >> 5;
    const int mbase = (wave & 1) * 64, nbase = (wave >> 1) * 64;

    #pragma unroll
    for (int mi = 0; mi < 2; mi++) {
        const int rowb = mt * BM + mbase + mi * 32;
        #pragma unroll
        for (int r = 0; r < 16; r++) {
            int rowit = (r & 3) + 8 * (r >> 2) + 4 * half;
            int row = rowb + rowit;
            float rl = 1.0f / lsum[b * T + row];
            size_t obase = ((size_t)b * T + row) * E + nt * BN + nbase + l31;
            out[obase] = acc[mi][0][r] * rl;
            out[obase + 32] = acc[mi][1][r] * rl;
        }
    }
}

extern "C" void kernel_launch(void* const* d_in, const int* in_sizes, int n_in,
                              void* d_out, int out_size, void* d_ws, size_t ws_size,
                              hipStream_t stream) {
    const float* q = (const float*)d_in[0];
    const float* k = (const float*)d_in[1];
    const float* v = (const float*)d_in[2];
    float* out = (float*)d_out;

    // ws: [lsum 32KB][QB 16.78MB (later aliased by VT)][KB 16.78MB][P 67.1MB] = ~96 MiB
    float* lsum = (float*)d_ws;
    unsigned short* qbw = (unsigned short*)((char*)d_ws + 32768);
    unsigned short* kbw = qbw + (size_t)NB * T * E;
    unsigned short* Pw  = kbw + (size_t)NB * T * E;
    unsigned short* vtw = qbw;  // VT written after pass1 finishes reading QB

    const int cvt_blocks = (int)((size_t)NB * T * E / (256 * 8));  // 4096
    cvt_bf16<<<cvt_blocks, 256, 0, stream>>>(q, qbw);
    cvt_bf16<<<cvt_blocks, 256, 0, stream>>>(k, kbw);
    zerof<<<NB * T / 256, 256, 0, stream>>>(lsum);

    pass1<<<NB * 32 * 32, 256, 0, stream>>>(qbw, kbw, Pw, lsum);

    v_transpose<<<NB * 64 * 16, 256, 0, stream>>>(v, vtw);

    pass2<<<NB * 32 * 8, 256, 0, stream>>>(Pw, vtw, lsum, out);
}

// Round 3
// 336.077 us; speedup vs baseline: 2.9282x; 1.1672x over previous
//
#include <hip/hip_runtime.h>

using short8  = __attribute__((ext_vector_type(8))) short;
using ushort8 = __attribute__((ext_vector_type(8))) unsigned short;
using f32x4   = __attribute__((ext_vector_type(4))) float;

#define T 4096
#define E 1024
#define NB 2
#define BM 128
#define BN 128
#define BK 32

__device__ __forceinline__ unsigned short f2bf(float f) {
    unsigned int u = __builtin_bit_cast(unsigned int, f);
    u = (u + 0x7FFFu + ((u >> 16) & 1u)) >> 16;
    return (unsigned short)u;
}
__device__ __forceinline__ float bf2f(unsigned short h) {
    unsigned int u = ((unsigned int)h) << 16;
    return __builtin_bit_cast(float, u);
}

__device__ __forceinline__ void gld16(const unsigned short* g, unsigned short* l) {
    __builtin_amdgcn_global_load_lds(
        (__attribute__((address_space(1))) void*)g,
        (__attribute__((address_space(3))) void*)l, 16, 0, 0);
}

// prologue: blocks [0,4096): q->bf16; [4096,8192): k->bf16; [8192,8224): zero lsum
__global__ __launch_bounds__(256) void prologue(const float* __restrict__ q,
                                                const float* __restrict__ k,
                                                unsigned short* __restrict__ qb,
                                                unsigned short* __restrict__ kb,
                                                float* __restrict__ lsum) {
    int bid = blockIdx.x;
    if (bid < 8192) {
        const float* src = (bid < 4096) ? q : k;
        unsigned short* dst = (bid < 4096) ? qb : kb;
        size_t i = ((size_t)(bid & 4095) * 256 + threadIdx.x) * 8;
        float4 f0 = *(const float4*)(src + i);
        float4 f1 = *(const float4*)(src + i + 4);
        ushort8 u;
        u[0]=f2bf(f0.x); u[1]=f2bf(f0.y); u[2]=f2bf(f0.z); u[3]=f2bf(f0.w);
        u[4]=f2bf(f1.x); u[5]=f2bf(f1.y); u[6]=f2bf(f1.z); u[7]=f2bf(f1.w);
        *(ushort8*)(dst + i) = u;
    } else {
        lsum[(bid - 8192) * 256 + threadIdx.x] = 0.0f;
    }
}

// V [b][t][e] fp32 -> VT [b][e][t] bf16
__global__ __launch_bounds__(256) void v_transpose(const float* __restrict__ v,
                                                   unsigned short* __restrict__ vt) {
    __shared__ float tile[64][65];
    int id  = blockIdx.x;
    int b   = id / (64 * 16);
    int rem = id % (64 * 16);
    int t0  = (rem / 16) * 64;
    int e0  = (rem % 16) * 64;
    int tid = threadIdx.x;
    int r   = tid >> 2;
    int c0  = (tid & 3) * 16;
    const float* src = v + ((size_t)(b * T + t0 + r)) * E + e0 + c0;
    #pragma unroll
    for (int i = 0; i < 4; i++) {
        float4 f = *(const float4*)(src + i * 4);
        tile[r][c0 + i*4 + 0] = f.x;
        tile[r][c0 + i*4 + 1] = f.y;
        tile[r][c0 + i*4 + 2] = f.z;
        tile[r][c0 + i*4 + 3] = f.w;
    }
    __syncthreads();
    int er = tid >> 2;
    #pragma unroll
    for (int ch = 0; ch < 2; ch++) {
        int tl = (tid & 3) * 16 + ch * 8;
        ushort8 u;
        #pragma unroll
        for (int j = 0; j < 8; j++) u[j] = f2bf(tile[tl + j][er]);
        *(ushort8*)(vt + ((size_t)(b * E + e0 + er)) * T + t0 + tl) = u;
    }
}

// 128x128xBK GEMM core, 16x16x32 MFMA, 4x4 frags per wave (intensity 64 FLOP/LDS-byte).
// LDS layout (per tile, 512 chunks of 16B): logical (row r, k-quad kq) at phys chunk
//   p = r*4 + (kq ^ ((r>>1)&3))        [XOR swizzle kills ds_read_b128 bank conflicts]
// Writer (global_load_lds, phys chunk p = call*256 + tid): r = p>>2, kq = (p&3)^((p>>3)&3).
// Frag read (A[m=lane&15][k=(lane>>4)*8+j]): 8 consecutive lanes hit 8 distinct bank groups.
template <int KITERS>
__device__ __forceinline__ void gemm_core(const unsigned short* Abase, int apitch,
                                          const unsigned short* Bbase, int bpitch,
                                          unsigned short* ldsA, unsigned short* ldsB,
                                          int tid, f32x4 (&acc)[4][4]) {
    const int lane = tid & 63, wave = tid >> 6;
    const int l15 = lane & 15, kq = lane >> 4;
    const int wm = (wave & 1) * 64, wn = (wave >> 1) * 64;

    const unsigned short* ga[2];
    const unsigned short* gb[2];
    unsigned short* la[2];
    unsigned short* lb[2];
    #pragma unroll
    for (int i = 0; i < 2; i++) {
        int p  = i * 256 + tid;
        int r  = p >> 2;
        int kqw = (p & 3) ^ ((p >> 3) & 3);
        ga[i] = Abase + (size_t)r * apitch + kqw * 8;
        gb[i] = Bbase + (size_t)r * bpitch + kqw * 8;
        la[i] = ldsA + (i * 256 + wave * 64) * 8;
        lb[i] = ldsB + (i * 256 + wave * 64) * 8;
    }
    int aoff[4], boff[4];
    #pragma unroll
    for (int mi = 0; mi < 4; mi++) {
        int r = wm + mi * 16 + l15;
        aoff[mi] = (r * 4 + (kq ^ ((r >> 1) & 3))) * 8;
        int rn = wn + mi * 16 + l15;
        boff[mi] = (rn * 4 + (kq ^ ((rn >> 1) & 3))) * 8;
    }

    for (int kt = 0; kt < KITERS; kt++) {
        __syncthreads();
        gld16(ga[0] + kt * BK, la[0]);
        gld16(ga[1] + kt * BK, la[1]);
        gld16(gb[0] + kt * BK, lb[0]);
        gld16(gb[1] + kt * BK, lb[1]);
        __syncthreads();
        short8 af[4], bf[4];
        #pragma unroll
        for (int i = 0; i < 4; i++) {
            af[i] = *(const short8*)(ldsA + aoff[i]);
            bf[i] = *(const short8*)(ldsB + boff[i]);
        }
        #pragma unroll
        for (int mi = 0; mi < 4; mi++)
            #pragma unroll
            for (int ni = 0; ni < 4; ni++)
                acc[mi][ni] = __builtin_amdgcn_mfma_f32_16x16x32_bf16(af[mi], bf[ni], acc[mi][ni], 0, 0, 0);
    }
}

// Pass 1: P = exp2(scale*log2e*(Q K^T) - 12) [bf16], lsum += row sums [fp32]
__global__ __launch_bounds__(256, 2) void pass1(const unsigned short* __restrict__ qb,
                                                const unsigned short* __restrict__ kb,
                                                unsigned short* __restrict__ P,
                                                float* __restrict__ lsum) {
    __shared__ unsigned short ldsA[BM * BK];
    __shared__ unsigned short ldsB[BN * BK];
    const int bx = blockIdx.x;
    const int b = bx >> 10, mt = (bx >> 5) & 31, nt = bx & 31;
    const int tid = threadIdx.x;

    f32x4 acc[4][4];
    #pragma unroll
    for (int i = 0; i < 4; i++)
        #pragma unroll
        for (int j = 0; j < 4; j++) acc[i][j] = {};

    gemm_core<E / BK>(qb + ((size_t)b * T + mt * BM) * E, E,
                      kb + ((size_t)b * T + nt * BN) * E, E,
                      ldsA, ldsB, tid, acc);

    const int lane = tid & 63, wave = tid >> 6;
    const int wm = (wave & 1) * 64, wn = (wave >> 1) * 64;
    const int quad = lane >> 4, l15 = lane & 15;
    const float sl2 = 0.0625f * 1.44269504089f;
    const int col0 = nt * BN + wn + l15;

    #pragma unroll
    for (int mi = 0; mi < 4; mi++) {
        #pragma unroll
        for (int r = 0; r < 4; r++) {
            int row = mt * BM + wm + mi * 16 + quad * 4 + r;
            size_t base = ((size_t)b * T + row) * T + col0;
            float s = 0.0f;
            #pragma unroll
            for (int ni = 0; ni < 4; ni++) {
                float p = exp2f(acc[mi][ni][r] * sl2 - 12.0f);
                unsigned short h = f2bf(p);
                P[base + ni * 16] = h;
                s += bf2f(h);
            }
            s += __shfl_xor(s, 1);
            s += __shfl_xor(s, 2);
            s += __shfl_xor(s, 4);
            s += __shfl_xor(s, 8);
            if (l15 == 0) atomicAdd(lsum + b * T + row, s);
        }
    }
}

// Pass 2: O = (P @ V) / l ; B operand = VT [b][e][t]
__global__ __launch_bounds__(256, 2) void pass2(const unsigned short* __restrict__ P,
                                                const unsigned short* __restrict__ vt,
                                                const float* __restrict__ lsum,
                                                float* __restrict__ out) {
    __shared__ unsigned short ldsA[BM * BK];
    __shared__ unsigned short ldsB[BN * BK];
    const int bx = blockIdx.x;
    const int b = bx >> 8, mt = (bx >> 3) & 31, nt = bx & 7;
    const int tid = threadIdx.x;

    f32x4 acc[4][4];
    #pragma unroll
    for (int i = 0; i < 4; i++)
        #pragma unroll
        for (int j = 0; j < 4; j++) acc[i][j] = {};

    gemm_core<T / BK>(P + ((size_t)b * T + mt * BM) * T, T,
                      vt + ((size_t)b * E + nt * BN) * T, T,
                      ldsA, ldsB, tid, acc);

    const int lane = tid & 63, wave = tid >> 6;
    const int wm = (wave & 1) * 64, wn = (wave >> 1) * 64;
    const int quad = lane >> 4, l15 = lane & 15;
    const int col0 = nt * BN + wn + l15;

    #pragma unroll
    for (int mi = 0; mi < 4; mi++) {
        #pragma unroll
        for (int r = 0; r < 4; r++) {
            int row = mt * BM + wm + mi * 16 + quad * 4 + r;
            float rl = 1.0f / lsum[b * T + row];
            size_t base = ((size_t)b * T + row) * E + col0;
            #pragma unroll
            for (int ni = 0; ni < 4; ni++)
                out[base + ni * 16] = acc[mi][ni][r] * rl;
        }
    }
}

extern "C" void kernel_launch(void* const* d_in, const int* in_sizes, int n_in,
                              void* d_out, int out_size, void* d_ws, size_t ws_size,
                              hipStream_t stream) {
    const float* q = (const float*)d_in[0];
    const float* k = (const float*)d_in[1];
    const float* v = (const float*)d_in[2];
    float* out = (float*)d_out;

    // ws: [lsum 32KB][QB 16.78MB (aliased by VT after pass1)][KB 16.78MB][P 67.1MB]
    float* lsum = (float*)d_ws;
    unsigned short* qbw = (unsigned short*)((char*)d_ws + 32768);
    unsigned short* kbw = qbw + (size_t)NB * T * E;
    unsigned short* Pw  = kbw + (size_t)NB * T * E;
    unsigned short* vtw = qbw;

    prologue<<<8224, 256, 0, stream>>>(q, k, qbw, kbw, lsum);
    pass1<<<NB * 32 * 32, 256, 0, stream>>>(qbw, kbw, Pw, lsum);
    v_transpose<<<NB * 64 * 16, 256, 0, stream>>>(v, vtw);
    pass2<<<NB * 32 * 8, 256, 0, stream>>>(Pw, vtw, lsum, out);
}

// Round 4
// 313.039 us; speedup vs baseline: 3.1437x; 1.0736x over previous
//
#include <hip/hip_runtime.h>

using short8  = __attribute__((ext_vector_type(8))) short;
using ushort8 = __attribute__((ext_vector_type(8))) unsigned short;
using f32x4   = __attribute__((ext_vector_type(4))) float;

#define T 4096
#define E 1024
#define NB 2
#define BM 128
#define BN 128
#define BK 32
#define TILE_ELEMS (BM * BK)   // 4096 ushorts = 8 KB per A or B tile

__device__ __forceinline__ unsigned short f2bf(float f) {
    unsigned int u = __builtin_bit_cast(unsigned int, f);
    u = (u + 0x7FFFu + ((u >> 16) & 1u)) >> 16;
    return (unsigned short)u;
}
__device__ __forceinline__ float bf2f(unsigned short h) {
    unsigned int u = ((unsigned int)h) << 16;
    return __builtin_bit_cast(float, u);
}

__device__ __forceinline__ void gld16(const unsigned short* g, unsigned short* l) {
    __builtin_amdgcn_global_load_lds(
        (__attribute__((address_space(1))) void*)g,
        (__attribute__((address_space(3))) void*)l, 16, 0, 0);
}

// prologue: blocks [0,4096): q->bf16; [4096,8192): k->bf16; [8192,8224): zero lsum
__global__ __launch_bounds__(256) void prologue(const float* __restrict__ q,
                                                const float* __restrict__ k,
                                                unsigned short* __restrict__ qb,
                                                unsigned short* __restrict__ kb,
                                                float* __restrict__ lsum) {
    int bid = blockIdx.x;
    if (bid < 8192) {
        const float* src = (bid < 4096) ? q : k;
        unsigned short* dst = (bid < 4096) ? qb : kb;
        size_t i = ((size_t)(bid & 4095) * 256 + threadIdx.x) * 8;
        float4 f0 = *(const float4*)(src + i);
        float4 f1 = *(const float4*)(src + i + 4);
        ushort8 u;
        u[0]=f2bf(f0.x); u[1]=f2bf(f0.y); u[2]=f2bf(f0.z); u[3]=f2bf(f0.w);
        u[4]=f2bf(f1.x); u[5]=f2bf(f1.y); u[6]=f2bf(f1.z); u[7]=f2bf(f1.w);
        *(ushort8*)(dst + i) = u;
    } else {
        lsum[(bid - 8192) * 256 + threadIdx.x] = 0.0f;
    }
}

// V [b][t][e] fp32 -> VT [b][e][t] bf16
__global__ __launch_bounds__(256) void v_transpose(const float* __restrict__ v,
                                                   unsigned short* __restrict__ vt) {
    __shared__ float tile[64][65];
    int id  = blockIdx.x;
    int b   = id / (64 * 16);
    int rem = id % (64 * 16);
    int t0  = (rem / 16) * 64;
    int e0  = (rem % 16) * 64;
    int tid = threadIdx.x;
    int r   = tid >> 2;
    int c0  = (tid & 3) * 16;
    const float* src = v + ((size_t)(b * T + t0 + r)) * E + e0 + c0;
    #pragma unroll
    for (int i = 0; i < 4; i++) {
        float4 f = *(const float4*)(src + i * 4);
        tile[r][c0 + i*4 + 0] = f.x;
        tile[r][c0 + i*4 + 1] = f.y;
        tile[r][c0 + i*4 + 2] = f.z;
        tile[r][c0 + i*4 + 3] = f.w;
    }
    __syncthreads();
    int er = tid >> 2;
    #pragma unroll
    for (int ch = 0; ch < 2; ch++) {
        int tl = (tid & 3) * 16 + ch * 8;
        ushort8 u;
        #pragma unroll
        for (int j = 0; j < 8; j++) u[j] = f2bf(tile[tl + j][er]);
        *(ushort8*)(vt + ((size_t)(b * E + e0 + er)) * T + t0 + tl) = u;
    }
}

// 128x128xBK GEMM core, 16x16x32 MFMA, 4x4 frags/wave, XOR-swizzled LDS
// (conflict-free, verified r3: SQ_LDS_BANK_CONFLICT=0), NBUF-deep software
// pipeline with raw s_barrier + manual s_waitcnt vmcnt(4*D) so prefetch
// loads stay in flight across barriers (never drain to vmcnt(0)).
template <int KITERS, int NBUF>
__device__ __forceinline__ void gemm_core(const unsigned short* Abase, int apitch,
                                          const unsigned short* Bbase, int bpitch,
                                          unsigned short* ldsA, unsigned short* ldsB,
                                          int tid, f32x4 (&acc)[4][4]) {
    constexpr int D = NBUF - 1;   // prefetch distance
    const int lane = tid & 63, wave = tid >> 6;
    const int l15 = lane & 15, kq = lane >> 4;
    const int wm = (wave & 1) * 64, wn = (wave >> 1) * 64;

    const unsigned short* ga[2];
    const unsigned short* gb[2];
    int lo[2];
    #pragma unroll
    for (int i = 0; i < 2; i++) {
        int p = i * 256 + tid;
        int r = p >> 2;
        int kqw = (p & 3) ^ ((p >> 3) & 3);
        ga[i] = Abase + (size_t)r * apitch + kqw * 8;
        gb[i] = Bbase + (size_t)r * bpitch + kqw * 8;
        lo[i] = (i * 256 + wave * 64) * 8;
    }
    int aoff[4], boff[4];
    #pragma unroll
    for (int mi = 0; mi < 4; mi++) {
        int r = wm + mi * 16 + l15;
        aoff[mi] = (r * 4 + (kq ^ ((r >> 1) & 3))) * 8;
        int rn = wn + mi * 16 + l15;
        boff[mi] = (rn * 4 + (kq ^ ((rn >> 1) & 3))) * 8;
    }

    // initial prefetch of tiles 0..D-1 into buffers 0..D-1
    #pragma unroll
    for (int i = 0; i < D; i++) {
        gld16(ga[0] + i * BK, ldsA + i * TILE_ELEMS + lo[0]);
        gld16(ga[1] + i * BK, ldsA + i * TILE_ELEMS + lo[1]);
        gld16(gb[0] + i * BK, ldsB + i * TILE_ELEMS + lo[0]);
        gld16(gb[1] + i * BK, ldsB + i * TILE_ELEMS + lo[1]);
    }

    int cbuf = 0, pbuf = D, pkt = D;
    for (int kt = 0; kt < KITERS; kt++) {
        // (a) all waves done computing on the buffer we are about to overwrite
        asm volatile("s_barrier" ::: "memory");
        gld16(ga[0] + pkt * BK, ldsA + pbuf * TILE_ELEMS + lo[0]);
        gld16(ga[1] + pkt * BK, ldsA + pbuf * TILE_ELEMS + lo[1]);
        gld16(gb[0] + pkt * BK, ldsB + pbuf * TILE_ELEMS + lo[0]);
        gld16(gb[1] + pkt * BK, ldsB + pbuf * TILE_ELEMS + lo[1]);
        // wait only for tile kt (oldest 4 loads); kt+1..kt+D stay in flight
        if constexpr (D == 1) asm volatile("s_waitcnt vmcnt(4)" ::: "memory");
        else                  asm volatile("s_waitcnt vmcnt(8)" ::: "memory");
        // (b) tile kt visible to all waves
        asm volatile("s_barrier" ::: "memory");

        const unsigned short* A = ldsA + cbuf * TILE_ELEMS;
        const unsigned short* B = ldsB + cbuf * TILE_ELEMS;
        short8 af[4], bf[4];
        #pragma unroll
        for (int i = 0; i < 4; i++) {
            af[i] = *(const short8*)(A + aoff[i]);
            bf[i] = *(const short8*)(B + boff[i]);
        }
        #pragma unroll
        for (int mi = 0; mi < 4; mi++)
            #pragma unroll
            for (int ni = 0; ni < 4; ni++)
                acc[mi][ni] = __builtin_amdgcn_mfma_f32_16x16x32_bf16(af[mi], bf[ni], acc[mi][ni], 0, 0, 0);

        if (++cbuf == NBUF) cbuf = 0;
        if (++pbuf == NBUF) pbuf = 0;
        if (++pkt == KITERS) pkt = 0;   // wrapped prefetch at tail (harmless reload)
    }
}

// Pass 1: P = exp2(scale*log2e*(Q K^T) - 12) [bf16], lsum += row sums [fp32]
// XCD swizzle: 32 nt-siblings of one Q row-tile land on one XCD (bx%8).
__global__ __launch_bounds__(256, 2) void pass1(const unsigned short* __restrict__ qb,
                                                const unsigned short* __restrict__ kb,
                                                unsigned short* __restrict__ P,
                                                float* __restrict__ lsum) {
    __shared__ unsigned short ldsA[2 * TILE_ELEMS];
    __shared__ unsigned short ldsB[2 * TILE_ELEMS];
    const int bx = blockIdx.x;
    const int x = bx & 7, j = bx >> 3;          // j in [0,256)
    const int gm = x * 8 + (j & 7);             // global row-tile [0,64)
    const int nt = j >> 3;                      // [0,32)
    const int b = gm >> 5, mt = gm & 31;
    const int tid = threadIdx.x;

    f32x4 acc[4][4];
    #pragma unroll
    for (int i = 0; i < 4; i++)
        #pragma unroll
        for (int jj = 0; jj < 4; jj++) acc[i][jj] = {};

    gemm_core<E / BK, 2>(qb + ((size_t)b * T + mt * BM) * E, E,
                         kb + ((size_t)b * T + nt * BN) * E, E,
                         ldsA, ldsB, tid, acc);

    const int lane = tid & 63, wave = tid >> 6;
    const int wm = (wave & 1) * 64, wn = (wave >> 1) * 64;
    const int quad = lane >> 4, l15 = lane & 15;
    const float sl2 = 0.0625f * 1.44269504089f;
    const int col0 = nt * BN + wn + l15;

    #pragma unroll
    for (int mi = 0; mi < 4; mi++) {
        #pragma unroll
        for (int r = 0; r < 4; r++) {
            int row = mt * BM + wm + mi * 16 + quad * 4 + r;
            size_t base = ((size_t)b * T + row) * T + col0;
            float s = 0.0f;
            #pragma unroll
            for (int ni = 0; ni < 4; ni++) {
                float p = exp2f(acc[mi][ni][r] * sl2 - 12.0f);
                unsigned short h = f2bf(p);
                P[base + ni * 16] = h;
                s += bf2f(h);
            }
            s += __shfl_xor(s, 1);
            s += __shfl_xor(s, 2);
            s += __shfl_xor(s, 4);
            s += __shfl_xor(s, 8);
            if (l15 == 0) atomicAdd(lsum + b * T + row, s);
        }
    }
}

// Pass 2: O = (P @ V) / l ; B operand = VT [b][e][t]
// XCD swizzle: 8 nt-siblings of one P row-block land on one XCD.
__global__ __launch_bounds__(256, 2) void pass2(const unsigned short* __restrict__ P,
                                                const unsigned short* __restrict__ vt,
                                                const float* __restrict__ lsum,
                                                float* __restrict__ out) {
    __shared__ unsigned short ldsA[3 * TILE_ELEMS];
    __shared__ unsigned short ldsB[3 * TILE_ELEMS];
    const int bx = blockIdx.x;
    const int x = bx & 7, j = bx >> 3;          // j in [0,64)
    const int gm = x * 8 + (j & 7);             // global row-tile [0,64)
    const int nt = j >> 3;                      // [0,8)
    const int b = gm >> 5, mt = gm & 31;
    const int tid = threadIdx.x;

    f32x4 acc[4][4];
    #pragma unroll
    for (int i = 0; i < 4; i++)
        #pragma unroll
        for (int jj = 0; jj < 4; jj++) acc[i][jj] = {};

    gemm_core<T / BK, 3>(P + ((size_t)b * T + mt * BM) * T, T,
                         vt + ((size_t)b * E + nt * BN) * T, T,
                         ldsA, ldsB, tid, acc);

    const int lane = tid & 63, wave = tid >> 6;
    const int wm = (wave & 1) * 64, wn = (wave >> 1) * 64;
    const int quad = lane >> 4, l15 = lane & 15;
    const int col0 = nt * BN + wn + l15;

    #pragma unroll
    for (int mi = 0; mi < 4; mi++) {
        #pragma unroll
        for (int r = 0; r < 4; r++) {
            int row = mt * BM + wm + mi * 16 + quad * 4 + r;
            float rl = 1.0f / lsum[b * T + row];
            size_t base = ((size_t)b * T + row) * E + col0;
            #pragma unroll
            for (int ni = 0; ni < 4; ni++)
                out[base + ni * 16] = acc[mi][ni][r] * rl;
        }
    }
}

extern "C" void kernel_launch(void* const* d_in, const int* in_sizes, int n_in,
                              void* d_out, int out_size, void* d_ws, size_t ws_size,
                              hipStream_t stream) {
    const float* q = (const float*)d_in[0];
    const float* k = (const float*)d_in[1];
    const float* v = (const float*)d_in[2];
    float* out = (float*)d_out;

    // ws: [lsum 32KB][QB 16.78MB (aliased by VT after pass1)][KB 16.78MB][P 67.1MB]
    float* lsum = (float*)d_ws;
    unsigned short* qbw = (unsigned short*)((char*)d_ws + 32768);
    unsigned short* kbw = qbw + (size_t)NB * T * E;
    unsigned short* Pw  = kbw + (size_t)NB * T * E;
    unsigned short* vtw = qbw;

    prologue<<<8224, 256, 0, stream>>>(q, k, qbw, kbw, lsum);
    pass1<<<NB * 32 * 32, 256, 0, stream>>>(qbw, kbw, Pw, lsum);
    v_transpose<<<NB * 64 * 16, 256, 0, stream>>>(v, vtw);
    pass2<<<NB * 32 * 8, 256, 0, stream>>>(Pw, vtw, lsum, out);
}

// Round 5
// 308.125 us; speedup vs baseline: 3.1939x; 1.0159x over previous
//
#include <hip/hip_runtime.h>

using short8  = __attribute__((ext_vector_type(8))) short;
using ushort8 = __attribute__((ext_vector_type(8))) unsigned short;
using f32x4   = __attribute__((ext_vector_type(4))) float;

#define T 4096
#define E 1024
#define NB 2
#define BM 128
#define BN 128
#define BK 32
#define TILE_ELEMS (BM * BK)   // 4096 ushorts = 8 KB per A or B tile

__device__ __forceinline__ unsigned short f2bf(float f) {
    unsigned int u = __builtin_bit_cast(unsigned int, f);
    u = (u + 0x7FFFu + ((u >> 16) & 1u)) >> 16;
    return (unsigned short)u;
}

__device__ __forceinline__ void gld16(const unsigned short* g, unsigned short* l) {
    __builtin_amdgcn_global_load_lds(
        (__attribute__((address_space(1))) void*)g,
        (__attribute__((address_space(3))) void*)l, 16, 0, 0);
}

__device__ __forceinline__ void do_cvt(const float* __restrict__ src,
                                       unsigned short* __restrict__ dst, int blk) {
    size_t i = ((size_t)blk * 256 + threadIdx.x) * 8;
    float4 f0 = *(const float4*)(src + i);
    float4 f1 = *(const float4*)(src + i + 4);
    ushort8 u;
    u[0]=f2bf(f0.x); u[1]=f2bf(f0.y); u[2]=f2bf(f0.z); u[3]=f2bf(f0.w);
    u[4]=f2bf(f1.x); u[5]=f2bf(f1.y); u[6]=f2bf(f1.z); u[7]=f2bf(f1.w);
    *(ushort8*)(dst + i) = u;
}

__device__ __forceinline__ void do_vt(const float* __restrict__ v,
                                      unsigned short* __restrict__ vt, int id,
                                      float (*tile)[65]) {
    int b   = id / (64 * 16);
    int rem = id % (64 * 16);
    int t0  = (rem / 16) * 64;
    int e0  = (rem % 16) * 64;
    int tid = threadIdx.x;
    int r   = tid >> 2;
    int c0  = (tid & 3) * 16;
    const float* src = v + ((size_t)(b * T + t0 + r)) * E + e0 + c0;
    #pragma unroll
    for (int i = 0; i < 4; i++) {
        float4 f = *(const float4*)(src + i * 4);
        tile[r][c0 + i*4 + 0] = f.x;
        tile[r][c0 + i*4 + 1] = f.y;
        tile[r][c0 + i*4 + 2] = f.z;
        tile[r][c0 + i*4 + 3] = f.w;
    }
    __syncthreads();
    int er = tid >> 2;
    #pragma unroll
    for (int ch = 0; ch < 2; ch++) {
        int tl = (tid & 3) * 16 + ch * 8;
        ushort8 u;
        #pragma unroll
        for (int j = 0; j < 8; j++) u[j] = f2bf(tile[tl + j][er]);
        *(ushort8*)(vt + ((size_t)(b * E + e0 + er)) * T + t0 + tl) = u;
    }
}

// fused prep: [0,4096) q->bf16 | [4096,8192) k->bf16 | [8192,10240) v-transpose | [10240,10272) zero lsum
__global__ __launch_bounds__(256) void prep(const float* __restrict__ q,
                                            const float* __restrict__ k,
                                            const float* __restrict__ v,
                                            unsigned short* __restrict__ qb,
                                            unsigned short* __restrict__ kb,
                                            unsigned short* __restrict__ vt,
                                            float* __restrict__ lsum) {
    __shared__ float tile[64][65];
    int bid = blockIdx.x;
    if (bid < 4096)        do_cvt(q, qb, bid);
    else if (bid < 8192)   do_cvt(k, kb, bid - 4096);
    else if (bid < 10240)  do_vt(v, vt, bid - 8192, tile);
    else                   lsum[(bid - 10240) * 256 + threadIdx.x] = 0.0f;
}

// fallback pieces (aliased-ws path)
__global__ __launch_bounds__(256) void prologue(const float* __restrict__ q,
                                                const float* __restrict__ k,
                                                unsigned short* __restrict__ qb,
                                                unsigned short* __restrict__ kb,
                                                float* __restrict__ lsum) {
    int bid = blockIdx.x;
    if (bid < 4096)      do_cvt(q, qb, bid);
    else if (bid < 8192) do_cvt(k, kb, bid - 4096);
    else                 lsum[(bid - 8192) * 256 + threadIdx.x] = 0.0f;
}
__global__ __launch_bounds__(256) void v_transpose(const float* __restrict__ v,
                                                   unsigned short* __restrict__ vt) {
    __shared__ float tile[64][65];
    do_vt(v, vt, blockIdx.x, tile);
}

// 128x128xBK GEMM core, 16x16x32 MFMA, 4x4 frags/wave, XOR-swizzled LDS
// (conflict-free: r3 SQ_LDS_BANK_CONFLICT=0), NBUF-deep pipeline with raw
// s_barrier + s_waitcnt vmcnt(4*D) so prefetches stay in flight across barriers.
template <int KITERS, int NBUF>
__device__ __forceinline__ void gemm_core(const unsigned short* Abase, int apitch,
                                          const unsigned short* Bbase, int bpitch,
                                          unsigned short* ldsA, unsigned short* ldsB,
                                          int tid, f32x4 (&acc)[4][4]) {
    constexpr int D = NBUF - 1;
    const int lane = tid & 63, wave = tid >> 6;
    const int l15 = lane & 15, kq = lane >> 4;
    const int wm = (wave & 1) * 64, wn = (wave >> 1) * 64;

    const unsigned short* ga[2];
    const unsigned short* gb[2];
    int lo[2];
    #pragma unroll
    for (int i = 0; i < 2; i++) {
        int p = i * 256 + tid;
        int r = p >> 2;
        int kqw = (p & 3) ^ ((p >> 3) & 3);
        ga[i] = Abase + (size_t)r * apitch + kqw * 8;
        gb[i] = Bbase + (size_t)r * bpitch + kqw * 8;
        lo[i] = (i * 256 + wave * 64) * 8;
    }
    int aoff[4], boff[4];
    #pragma unroll
    for (int mi = 0; mi < 4; mi++) {
        int r = wm + mi * 16 + l15;
        aoff[mi] = (r * 4 + (kq ^ ((r >> 1) & 3))) * 8;
        int rn = wn + mi * 16 + l15;
        boff[mi] = (rn * 4 + (kq ^ ((rn >> 1) & 3))) * 8;
    }

    #pragma unroll
    for (int i = 0; i < D; i++) {
        gld16(ga[0] + i * BK, ldsA + i * TILE_ELEMS + lo[0]);
        gld16(ga[1] + i * BK, ldsA + i * TILE_ELEMS + lo[1]);
        gld16(gb[0] + i * BK, ldsB + i * TILE_ELEMS + lo[0]);
        gld16(gb[1] + i * BK, ldsB + i * TILE_ELEMS + lo[1]);
    }

    int cbuf = 0, pbuf = D, pkt = D;
    for (int kt = 0; kt < KITERS; kt++) {
        asm volatile("s_barrier" ::: "memory");
        gld16(ga[0] + pkt * BK, ldsA + pbuf * TILE_ELEMS + lo[0]);
        gld16(ga[1] + pkt * BK, ldsA + pbuf * TILE_ELEMS + lo[1]);
        gld16(gb[0] + pkt * BK, ldsB + pbuf * TILE_ELEMS + lo[0]);
        gld16(gb[1] + pkt * BK, ldsB + pbuf * TILE_ELEMS + lo[1]);
        if constexpr (D == 1) asm volatile("s_waitcnt vmcnt(4)" ::: "memory");
        else                  asm volatile("s_waitcnt vmcnt(8)" ::: "memory");
        asm volatile("s_barrier" ::: "memory");

        const unsigned short* A = ldsA + cbuf * TILE_ELEMS;
        const unsigned short* B = ldsB + cbuf * TILE_ELEMS;
        short8 af[4], bf[4];
        #pragma unroll
        for (int i = 0; i < 4; i++) {
            af[i] = *(const short8*)(A + aoff[i]);
            bf[i] = *(const short8*)(B + boff[i]);
        }
        #pragma unroll
        for (int mi = 0; mi < 4; mi++)
            #pragma unroll
            for (int ni = 0; ni < 4; ni++)
                acc[mi][ni] = __builtin_amdgcn_mfma_f32_16x16x32_bf16(af[mi], bf[ni], acc[mi][ni], 0, 0, 0);

        if (++cbuf == NBUF) cbuf = 0;
        if (++pbuf == NBUF) pbuf = 0;
        if (++pkt == KITERS) pkt = 0;
    }
}

// Pass 1: P = exp2(scale*log2e*(Q K^T) - 12) [bf16], lsum += row sums [fp32]
__global__ __launch_bounds__(256, 2) void pass1(const unsigned short* __restrict__ qb,
                                                const unsigned short* __restrict__ kb,
                                                unsigned short* __restrict__ P,
                                                float* __restrict__ lsum) {
    __shared__ unsigned short ldsA[3 * TILE_ELEMS];
    __shared__ unsigned short ldsB[3 * TILE_ELEMS];
    const int bx = blockIdx.x;
    const int x = bx & 7, j = bx >> 3;
    const int gm = x * 8 + (j & 7);
    const int nt = j >> 3;
    const int b = gm >> 5, mt = gm & 31;
    const int tid = threadIdx.x;

    f32x4 acc[4][4];
    #pragma unroll
    for (int i = 0; i < 4; i++)
        #pragma unroll
        for (int jj = 0; jj < 4; jj++) acc[i][jj] = {};

    gemm_core<E / BK, 3>(qb + ((size_t)b * T + mt * BM) * E, E,
                         kb + ((size_t)b * T + nt * BN) * E, E,
                         ldsA, ldsB, tid, acc);

    const int lane = tid & 63, wave = tid >> 6;
    const int wm = (wave & 1) * 64, wn = (wave >> 1) * 64;
    const int quad = lane >> 4, l15 = lane & 15;
    const float sl2 = 0.0625f * 1.44269504089f;
    const int col0 = nt * BN + wn + l15;

    #pragma unroll
    for (int mi = 0; mi < 4; mi++) {
        #pragma unroll
        for (int r = 0; r < 4; r++) {
            int row = mt * BM + wm + mi * 16 + quad * 4 + r;
            size_t base = ((size_t)b * T + row) * T + col0;
            float s = 0.0f;
            #pragma unroll
            for (int ni = 0; ni < 4; ni++) {
                float p = exp2f(acc[mi][ni][r] * sl2 - 12.0f);
                P[base + ni * 16] = f2bf(p);
                s += p;
            }
            s += __shfl_xor(s, 1);
            s += __shfl_xor(s, 2);
            s += __shfl_xor(s, 4);
            s += __shfl_xor(s, 8);
            if (l15 == 0) atomicAdd(lsum + b * T + row, s);
        }
    }
}

// Pass 2: O = (P @ V) / l ; B operand = VT [b][e][t]
__global__ __launch_bounds__(256, 2) void pass2(const unsigned short* __restrict__ P,
                                                const unsigned short* __restrict__ vt,
                                                const float* __restrict__ lsum,
                                                float* __restrict__ out) {
    __shared__ unsigned short ldsA[3 * TILE_ELEMS];
    __shared__ unsigned short ldsB[3 * TILE_ELEMS];
    const int bx = blockIdx.x;
    const int x = bx & 7, j = bx >> 3;
    const int gm = x * 8 + (j & 7);
    const int nt = j >> 3;
    const int b = gm >> 5, mt = gm & 31;
    const int tid = threadIdx.x;

    f32x4 acc[4][4];
    #pragma unroll
    for (int i = 0; i < 4; i++)
        #pragma unroll
        for (int jj = 0; jj < 4; jj++) acc[i][jj] = {};

    gemm_core<T / BK, 3>(P + ((size_t)b * T + mt * BM) * T, T,
                         vt + ((size_t)b * E + nt * BN) * T, T,
                         ldsA, ldsB, tid, acc);

    const int lane = tid & 63, wave = tid >> 6;
    const int wm = (wave & 1) * 64, wn = (wave >> 1) * 64;
    const int quad = lane >> 4, l15 = lane & 15;
    const int col0 = nt * BN + wn + l15;

    #pragma unroll
    for (int mi = 0; mi < 4; mi++) {
        #pragma unroll
        for (int r = 0; r < 4; r++) {
            int row = mt * BM + wm + mi * 16 + quad * 4 + r;
            float rl = 1.0f / lsum[b * T + row];
            size_t base = ((size_t)b * T + row) * E + col0;
            #pragma unroll
            for (int ni = 0; ni < 4; ni++)
                out[base + ni * 16] = acc[mi][ni][r] * rl;
        }
    }
}

extern "C" void kernel_launch(void* const* d_in, const int* in_sizes, int n_in,
                              void* d_out, int out_size, void* d_ws, size_t ws_size,
                              hipStream_t stream) {
    const float* q = (const float*)d_in[0];
    const float* k = (const float*)d_in[1];
    const float* v = (const float*)d_in[2];
    float* out = (float*)d_out;

    const size_t QK = (size_t)NB * T * E;        // elems per Q/K/VT buffer
    const size_t PSZ = (size_t)NB * T * T;
    float* lsum = (float*)d_ws;
    unsigned short* qbw = (unsigned short*)((char*)d_ws + 32768);
    unsigned short* kbw = qbw + QK;
    unsigned short* Pw  = kbw + QK;

    const size_t full_need = 32768 + (3 * QK + PSZ) * sizeof(unsigned short);

    if (ws_size >= full_need) {
        // roomy path: VT gets its own region -> fuse all prep into one kernel
        unsigned short* vtw = Pw + PSZ;
        prep<<<10272, 256, 0, stream>>>(q, k, v, qbw, kbw, vtw, lsum);
        pass1<<<NB * 32 * 32, 256, 0, stream>>>(qbw, kbw, Pw, lsum);
        pass2<<<NB * 32 * 8, 256, 0, stream>>>(Pw, vtw, lsum, out);
    } else {
        // tight path: VT aliases QB (valid only after pass1 consumed QB)
        unsigned short* vtw = qbw;
        prologue<<<8224, 256, 0, stream>>>(q, k, qbw, kbw, lsum);
        pass1<<<NB * 32 * 32, 256, 0, stream>>>(qbw, kbw, Pw, lsum);
        v_transpose<<<NB * 64 * 16, 256, 0, stream>>>(v, vtw);
        pass2<<<NB * 32 * 8, 256, 0, stream>>>(Pw, vtw, lsum, out);
    }
}

// Round 6
// 294.464 us; speedup vs baseline: 3.3420x; 1.0464x over previous
//
#include <hip/hip_runtime.h>

using short8  = __attribute__((ext_vector_type(8))) short;
using ushort8 = __attribute__((ext_vector_type(8))) unsigned short;
using f32x4   = __attribute__((ext_vector_type(4))) float;

#define T 4096
#define E 1024
#define NB 2
#define BM 128
#define BN 128
#define BK 32
#define TILE_ELEMS (BM * BK)     // 4096 ushorts = 8 KB (128-row tile)
#define TILE_A_W   (256 * BK)    // 8192 ushorts = 16 KB (256-row tile)

__device__ __forceinline__ unsigned short f2bf(float f) {
    unsigned int u = __builtin_bit_cast(unsigned int, f);
    u = (u + 0x7FFFu + ((u >> 16) & 1u)) >> 16;
    return (unsigned short)u;
}

__device__ __forceinline__ void gld16(const unsigned short* g, unsigned short* l) {
    __builtin_amdgcn_global_load_lds(
        (__attribute__((address_space(1))) void*)g,
        (__attribute__((address_space(3))) void*)l, 16, 0, 0);
}

__device__ __forceinline__ void do_cvt(const float* __restrict__ src,
                                       unsigned short* __restrict__ dst, int blk) {
    size_t i = ((size_t)blk * 256 + threadIdx.x) * 8;
    float4 f0 = *(const float4*)(src + i);
    float4 f1 = *(const float4*)(src + i + 4);
    ushort8 u;
    u[0]=f2bf(f0.x); u[1]=f2bf(f0.y); u[2]=f2bf(f0.z); u[3]=f2bf(f0.w);
    u[4]=f2bf(f1.x); u[5]=f2bf(f1.y); u[6]=f2bf(f1.z); u[7]=f2bf(f1.w);
    *(ushort8*)(dst + i) = u;
}

__device__ __forceinline__ void do_vt(const float* __restrict__ v,
                                      unsigned short* __restrict__ vt, int id,
                                      float (*tile)[65]) {
    int b   = id / (64 * 16);
    int rem = id % (64 * 16);
    int t0  = (rem / 16) * 64;
    int e0  = (rem % 16) * 64;
    int tid = threadIdx.x;
    int r   = tid >> 2;
    int c0  = (tid & 3) * 16;
    const float* src = v + ((size_t)(b * T + t0 + r)) * E + e0 + c0;
    #pragma unroll
    for (int i = 0; i < 4; i++) {
        float4 f = *(const float4*)(src + i * 4);
        tile[r][c0 + i*4 + 0] = f.x;
        tile[r][c0 + i*4 + 1] = f.y;
        tile[r][c0 + i*4 + 2] = f.z;
        tile[r][c0 + i*4 + 3] = f.w;
    }
    __syncthreads();
    int er = tid >> 2;
    #pragma unroll
    for (int ch = 0; ch < 2; ch++) {
        int tl = (tid & 3) * 16 + ch * 8;
        ushort8 u;
        #pragma unroll
        for (int j = 0; j < 8; j++) u[j] = f2bf(tile[tl + j][er]);
        *(ushort8*)(vt + ((size_t)(b * E + e0 + er)) * T + t0 + tl) = u;
    }
}

// fused prep: [0,4096) q | [4096,8192) k | [8192,10240) v-transpose | [10240,10272) zero lsum
__global__ __launch_bounds__(256) void prep(const float* __restrict__ q,
                                            const float* __restrict__ k,
                                            const float* __restrict__ v,
                                            unsigned short* __restrict__ qb,
                                            unsigned short* __restrict__ kb,
                                            unsigned short* __restrict__ vt,
                                            float* __restrict__ lsum) {
    __shared__ float tile[64][65];
    int bid = blockIdx.x;
    if (bid < 4096)        do_cvt(q, qb, bid);
    else if (bid < 8192)   do_cvt(k, kb, bid - 4096);
    else if (bid < 10240)  do_vt(v, vt, bid - 8192, tile);
    else                   lsum[(bid - 10240) * 256 + threadIdx.x] = 0.0f;
}

// fallback pieces (aliased-ws path)
__global__ __launch_bounds__(256) void prologue(const float* __restrict__ q,
                                                const float* __restrict__ k,
                                                unsigned short* __restrict__ qb,
                                                unsigned short* __restrict__ kb,
                                                float* __restrict__ lsum) {
    int bid = blockIdx.x;
    if (bid < 4096)      do_cvt(q, qb, bid);
    else if (bid < 8192) do_cvt(k, kb, bid - 4096);
    else                 lsum[(bid - 8192) * 256 + threadIdx.x] = 0.0f;
}
__global__ __launch_bounds__(256) void v_transpose(const float* __restrict__ v,
                                                   unsigned short* __restrict__ vt) {
    __shared__ float tile[64][65];
    do_vt(v, vt, blockIdx.x, tile);
}

// ---------- 128x128xBK core (pass2), NBUF-deep pipeline, raw barriers ----------
template <int KITERS, int NBUF>
__device__ __forceinline__ void gemm_core(const unsigned short* Abase, int apitch,
                                          const unsigned short* Bbase, int bpitch,
                                          unsigned short* ldsA, unsigned short* ldsB,
                                          int tid, f32x4 (&acc)[4][4]) {
    constexpr int D = NBUF - 1;
    const int lane = tid & 63, wave = tid >> 6;
    const int l15 = lane & 15, kq = lane >> 4;
    const int wm = (wave & 1) * 64, wn = (wave >> 1) * 64;

    const unsigned short* ga[2];
    const unsigned short* gb[2];
    int lo[2];
    #pragma unroll
    for (int i = 0; i < 2; i++) {
        int p = i * 256 + tid;
        int r = p >> 2;
        int kqw = (p & 3) ^ ((p >> 3) & 3);
        ga[i] = Abase + (size_t)r * apitch + kqw * 8;
        gb[i] = Bbase + (size_t)r * bpitch + kqw * 8;
        lo[i] = (i * 256 + wave * 64) * 8;
    }
    int aoff[4], boff[4];
    #pragma unroll
    for (int mi = 0; mi < 4; mi++) {
        int r = wm + mi * 16 + l15;
        aoff[mi] = (r * 4 + (kq ^ ((r >> 1) & 3))) * 8;
        int rn = wn + mi * 16 + l15;
        boff[mi] = (rn * 4 + (kq ^ ((rn >> 1) & 3))) * 8;
    }

    #pragma unroll
    for (int i = 0; i < D; i++) {
        gld16(ga[0] + i * BK, ldsA + i * TILE_ELEMS + lo[0]);
        gld16(ga[1] + i * BK, ldsA + i * TILE_ELEMS + lo[1]);
        gld16(gb[0] + i * BK, ldsB + i * TILE_ELEMS + lo[0]);
        gld16(gb[1] + i * BK, ldsB + i * TILE_ELEMS + lo[1]);
    }

    int cbuf = 0, pbuf = D, pkt = D;
    for (int kt = 0; kt < KITERS; kt++) {
        asm volatile("s_barrier" ::: "memory");
        gld16(ga[0] + pkt * BK, ldsA + pbuf * TILE_ELEMS + lo[0]);
        gld16(ga[1] + pkt * BK, ldsA + pbuf * TILE_ELEMS + lo[1]);
        gld16(gb[0] + pkt * BK, ldsB + pbuf * TILE_ELEMS + lo[0]);
        gld16(gb[1] + pkt * BK, ldsB + pbuf * TILE_ELEMS + lo[1]);
        if constexpr (D == 1) asm volatile("s_waitcnt vmcnt(4)" ::: "memory");
        else                  asm volatile("s_waitcnt vmcnt(8)" ::: "memory");
        asm volatile("s_barrier" ::: "memory");

        const unsigned short* A = ldsA + cbuf * TILE_ELEMS;
        const unsigned short* B = ldsB + cbuf * TILE_ELEMS;
        short8 af[4], bf[4];
        #pragma unroll
        for (int i = 0; i < 4; i++) {
            af[i] = *(const short8*)(A + aoff[i]);
            bf[i] = *(const short8*)(B + boff[i]);
        }
        #pragma unroll
        for (int mi = 0; mi < 4; mi++)
            #pragma unroll
            for (int ni = 0; ni < 4; ni++)
                acc[mi][ni] = __builtin_amdgcn_mfma_f32_16x16x32_bf16(af[mi], bf[ni], acc[mi][ni], 0, 0, 0);

        if (++cbuf == NBUF) cbuf = 0;
        if (++pbuf == NBUF) pbuf = 0;
        if (++pkt == KITERS) pkt = 0;
    }
}

// ---------- 256x128xBK core (pass1), 512 threads, NBUF=2 ----------
// Intensity 87 FLOP/staged-byte (vs 64 for 128x128): attacks the L2-staging bound.
template <int KITERS>
__device__ __forceinline__ void gemm_core_wide(const unsigned short* Abase, int apitch,
                                               const unsigned short* Bbase, int bpitch,
                                               unsigned short* ldsA, unsigned short* ldsB,
                                               int tid, f32x4 (&acc)[4][4]) {
    const int lane = tid & 63, wave = tid >> 6;          // wave 0..7
    const int l15 = lane & 15, kq = lane >> 4;
    const int wm = (wave & 3) * 64, wn = (wave >> 2) * 64;

    const unsigned short* ga[2];
    int lao[2];
    #pragma unroll
    for (int i = 0; i < 2; i++) {
        int p = i * 512 + tid;                            // A: 1024 chunks
        int r = p >> 2;
        int kqw = (p & 3) ^ ((p >> 3) & 3);
        ga[i] = Abase + (size_t)r * apitch + kqw * 8;
        lao[i] = (i * 512 + wave * 64) * 8;
    }
    const unsigned short* gb;
    int lbo;
    {
        int p = tid;                                      // B: 512 chunks
        int r = p >> 2;
        int kqw = (p & 3) ^ ((p >> 3) & 3);
        gb = Bbase + (size_t)r * bpitch + kqw * 8;
        lbo = (wave * 64) * 8;
    }
    int aoff[4], boff[4];
    #pragma unroll
    for (int mi = 0; mi < 4; mi++) {
        int r = wm + mi * 16 + l15;                       // [0,256)
        aoff[mi] = (r * 4 + (kq ^ ((r >> 1) & 3))) * 8;
        int rn = wn + mi * 16 + l15;                      // [0,128)
        boff[mi] = (rn * 4 + (kq ^ ((rn >> 1) & 3))) * 8;
    }

    // prefetch tile 0 -> buffer 0
    gld16(ga[0], ldsA + lao[0]);
    gld16(ga[1], ldsA + lao[1]);
    gld16(gb,    ldsB + lbo);

    int cbuf = 0;
    for (int kt = 0; kt < KITERS; kt++) {
        int nxt = (kt + 1 < KITERS) ? (kt + 1) : 0;       // tail reload is harmless
        int obuf = cbuf ^ 1;
        asm volatile("s_barrier" ::: "memory");           // done computing on obuf
        gld16(ga[0] + nxt * BK, ldsA + obuf * TILE_A_W + lao[0]);
        gld16(ga[1] + nxt * BK, ldsA + obuf * TILE_A_W + lao[1]);
        gld16(gb    + nxt * BK, ldsB + obuf * TILE_ELEMS + lbo);
        asm volatile("s_waitcnt vmcnt(3)" ::: "memory");  // tile kt landed; kt+1 in flight
        asm volatile("s_barrier" ::: "memory");

        const unsigned short* A = ldsA + cbuf * TILE_A_W;
        const unsigned short* B = ldsB + cbuf * TILE_ELEMS;
        short8 af[4], bf[4];
        #pragma unroll
        for (int i = 0; i < 4; i++) {
            af[i] = *(const short8*)(A + aoff[i]);
            bf[i] = *(const short8*)(B + boff[i]);
        }
        #pragma unroll
        for (int mi = 0; mi < 4; mi++)
            #pragma unroll
            for (int ni = 0; ni < 4; ni++)
                acc[mi][ni] = __builtin_amdgcn_mfma_f32_16x16x32_bf16(af[mi], bf[ni], acc[mi][ni], 0, 0, 0);

        cbuf = obuf;
    }
}

// Pass 1: P = exp2(scale*log2e*(Q K^T) - 12) [bf16], lsum += row sums [fp32]
// 256x128 tile, 512 threads. XCD swizzle: 4 row-tiles x 32 nt per XCD.
__global__ __launch_bounds__(512, 2) void pass1(const unsigned short* __restrict__ qb,
                                                const unsigned short* __restrict__ kb,
                                                unsigned short* __restrict__ P,
                                                float* __restrict__ lsum) {
    __shared__ unsigned short ldsA[2 * TILE_A_W];    // 32 KB
    __shared__ unsigned short ldsB[2 * TILE_ELEMS];  // 16 KB
    const int bx = blockIdx.x;
    const int x = bx & 7, j = bx >> 3;               // j in [0,128)
    const int gm = x * 4 + (j & 3);                  // [0,32): b*16+mt
    const int nt = j >> 2;                           // [0,32)
    const int b = gm >> 4, mt = gm & 15;
    const int tid = threadIdx.x;

    f32x4 acc[4][4];
    #pragma unroll
    for (int i = 0; i < 4; i++)
        #pragma unroll
        for (int jj = 0; jj < 4; jj++) acc[i][jj] = {};

    gemm_core_wide<E / BK>(qb + ((size_t)b * T + mt * 256) * E, E,
                           kb + ((size_t)b * T + nt * BN) * E, E,
                           ldsA, ldsB, tid, acc);

    const int lane = tid & 63, wave = tid >> 6;
    const int wm = (wave & 3) * 64, wn = (wave >> 2) * 64;
    const int quad = lane >> 4, l15 = lane & 15;
    const float sl2 = 0.0625f * 1.44269504089f;
    const int col0 = nt * BN + wn + l15;

    #pragma unroll
    for (int mi = 0; mi < 4; mi++) {
        #pragma unroll
        for (int r = 0; r < 4; r++) {
            int row = mt * 256 + wm + mi * 16 + quad * 4 + r;
            size_t base = ((size_t)b * T + row) * T + col0;
            float s = 0.0f;
            #pragma unroll
            for (int ni = 0; ni < 4; ni++) {
                float p = exp2f(acc[mi][ni][r] * sl2 - 12.0f);
                P[base + ni * 16] = f2bf(p);
                s += p;
            }
            s += __shfl_xor(s, 1);
            s += __shfl_xor(s, 2);
            s += __shfl_xor(s, 4);
            s += __shfl_xor(s, 8);
            if (l15 == 0) atomicAdd(lsum + b * T + row, s);
        }
    }
}

// Pass 2: O = (P @ V) / l ; B operand = VT [b][e][t]
__global__ __launch_bounds__(256, 2) void pass2(const unsigned short* __restrict__ P,
                                                const unsigned short* __restrict__ vt,
                                                const float* __restrict__ lsum,
                                                float* __restrict__ out) {
    __shared__ unsigned short ldsA[3 * TILE_ELEMS];
    __shared__ unsigned short ldsB[3 * TILE_ELEMS];
    const int bx = blockIdx.x;
    const int x = bx & 7, j = bx >> 3;
    const int gm = x * 8 + (j & 7);
    const int nt = j >> 3;
    const int b = gm >> 5, mt = gm & 31;
    const int tid = threadIdx.x;

    f32x4 acc[4][4];
    #pragma unroll
    for (int i = 0; i < 4; i++)
        #pragma unroll
        for (int jj = 0; jj < 4; jj++) acc[i][jj] = {};

    gemm_core<T / BK, 3>(P + ((size_t)b * T + mt * BM) * T, T,
                         vt + ((size_t)b * E + nt * BN) * T, T,
                         ldsA, ldsB, tid, acc);

    const int lane = tid & 63, wave = tid >> 6;
    const int wm = (wave & 1) * 64, wn = (wave >> 1) * 64;
    const int quad = lane >> 4, l15 = lane & 15;
    const int col0 = nt * BN + wn + l15;

    #pragma unroll
    for (int mi = 0; mi < 4; mi++) {
        #pragma unroll
        for (int r = 0; r < 4; r++) {
            int row = mt * BM + wm + mi * 16 + quad * 4 + r;
            float rl = 1.0f / lsum[b * T + row];
            size_t base = ((size_t)b * T + row) * E + col0;
            #pragma unroll
            for (int ni = 0; ni < 4; ni++)
                out[base + ni * 16] = acc[mi][ni][r] * rl;
        }
    }
}

extern "C" void kernel_launch(void* const* d_in, const int* in_sizes, int n_in,
                              void* d_out, int out_size, void* d_ws, size_t ws_size,
                              hipStream_t stream) {
    const float* q = (const float*)d_in[0];
    const float* k = (const float*)d_in[1];
    const float* v = (const float*)d_in[2];
    float* out = (float*)d_out;

    const size_t QK = (size_t)NB * T * E;
    const size_t PSZ = (size_t)NB * T * T;
    float* lsum = (float*)d_ws;
    unsigned short* qbw = (unsigned short*)((char*)d_ws + 32768);
    unsigned short* kbw = qbw + QK;
    unsigned short* Pw  = kbw + QK;

    const size_t full_need = 32768 + (3 * QK + PSZ) * sizeof(unsigned short);

    if (ws_size >= full_need) {
        unsigned short* vtw = Pw + PSZ;
        prep<<<10272, 256, 0, stream>>>(q, k, v, qbw, kbw, vtw, lsum);
        pass1<<<1024, 512, 0, stream>>>(qbw, kbw, Pw, lsum);
        pass2<<<NB * 32 * 8, 256, 0, stream>>>(Pw, vtw, lsum, out);
    } else {
        unsigned short* vtw = qbw;
        prologue<<<8224, 256, 0, stream>>>(q, k, qbw, kbw, lsum);
        pass1<<<1024, 512, 0, stream>>>(qbw, kbw, Pw, lsum);
        v_transpose<<<NB * 64 * 16, 256, 0, stream>>>(v, vtw);
        pass2<<<NB * 32 * 8, 256, 0, stream>>>(Pw, vtw, lsum, out);
    }
}